// Round 1
// baseline (25.689 us; speedup 1.0000x reference)
//
#include <hip/hip_runtime.h>

#define BDIM 256

// One thread = one batch element x.
// acc = sum over (a,b,c) of (lhs - rhs)^2 for that element.
// Deterministic two-kernel reduction: block partials -> d_ws, then 1-block finish.
__global__ __launch_bounds__(BDIM) void cg_main_kernel(
    const float* __restrict__ D1, const float* __restrict__ D2,
    const float* __restrict__ D3, const float* __restrict__ cg,
    float* __restrict__ partials, int batch)
{
    __shared__ float cg_s[105];            // cg[i,j,c] = cg_s[i*35 + j*7 + c]
    const int tid = threadIdx.x;
    if (tid < 105) cg_s[tid] = cg[tid];
    __syncthreads();

    const int x = blockIdx.x * BDIM + tid;
    float acc = 0.0f;
    if (x < batch) {
        const float* p1 = D1 + (size_t)x * 9;
        const float* p2 = D2 + (size_t)x * 25;
        const float* p3 = D3 + (size_t)x * 49;
        float d1[9], d2[25], d3[49];
        #pragma unroll
        for (int i = 0; i < 9; ++i)  d1[i] = p1[i];
        #pragma unroll
        for (int i = 0; i < 25; ++i) d2[i] = p2[i];
        #pragma unroll
        for (int i = 0; i < 49; ++i) d3[i] = p3[i];

        #pragma unroll
        for (int a = 0; a < 3; ++a) {
            // Ua[j][c] = sum_i D1[x,a,i] * cg[i,j,c]
            float Ua[35];
            #pragma unroll
            for (int j = 0; j < 5; ++j) {
                #pragma unroll
                for (int c = 0; c < 7; ++c) {
                    float u = d1[a*3+0] * cg_s[      j*7 + c];
                    u = fmaf(d1[a*3+1],  cg_s[35 +  j*7 + c], u);
                    u = fmaf(d1[a*3+2],  cg_s[70 +  j*7 + c], u);
                    Ua[j*7+c] = u;
                }
            }
            #pragma unroll
            for (int b = 0; b < 5; ++b) {
                float cgab[7];                       // cg[a,b,:]
                #pragma unroll
                for (int i = 0; i < 7; ++i) cgab[i] = cg_s[(a*5+b)*7 + i];
                #pragma unroll
                for (int c = 0; c < 7; ++c) {
                    float L = d2[b*5+0] * Ua[c];
                    #pragma unroll
                    for (int j = 1; j < 5; ++j) L = fmaf(d2[b*5+j], Ua[j*7+c], L);
                    float R = cgab[0] * d3[c];
                    #pragma unroll
                    for (int i = 1; i < 7; ++i) R = fmaf(cgab[i], d3[i*7+c], R);
                    const float r = L - R;
                    acc = fmaf(r, r, acc);
                }
            }
        }
    }

    // wave (64-lane) butterfly reduce, then cross-wave via LDS
    #pragma unroll
    for (int off = 32; off > 0; off >>= 1)
        acc += __shfl_down(acc, off, 64);
    __shared__ float wsum[BDIM / 64];
    if ((tid & 63) == 0) wsum[tid >> 6] = acc;
    __syncthreads();
    if (tid == 0) {
        float s = 0.0f;
        #pragma unroll
        for (int w = 0; w < BDIM / 64; ++w) s += wsum[w];
        partials[blockIdx.x] = s;
    }
}

__global__ __launch_bounds__(BDIM) void cg_reduce_kernel(
    const float* __restrict__ partials, float* __restrict__ out,
    int n, float inv)
{
    const int tid = threadIdx.x;
    float s = 0.0f;
    for (int i = tid; i < n; i += BDIM) s += partials[i];   // deterministic order
    #pragma unroll
    for (int off = 32; off > 0; off >>= 1)
        s += __shfl_down(s, off, 64);
    __shared__ float wsum[BDIM / 64];
    if ((tid & 63) == 0) wsum[tid >> 6] = s;
    __syncthreads();
    if (tid == 0) {
        float t = 0.0f;
        #pragma unroll
        for (int w = 0; w < BDIM / 64; ++w) t += wsum[w];
        out[0] = t * inv;
    }
}

extern "C" void kernel_launch(void* const* d_in, const int* in_sizes, int n_in,
                              void* d_out, int out_size, void* d_ws, size_t ws_size,
                              hipStream_t stream)
{
    const float* D1 = (const float*)d_in[0];
    const float* D2 = (const float*)d_in[1];
    const float* D3 = (const float*)d_in[2];
    const float* cg = (const float*)d_in[3];
    float* out      = (float*)d_out;
    float* partials = (float*)d_ws;       // nblocks floats (4 KB) of scratch

    const int batch   = in_sizes[0] / 9;          // 262144
    const int nblocks = (batch + BDIM - 1) / BDIM; // 1024
    const float inv   = 1.0f / ((float)batch * 105.0f);

    cg_main_kernel<<<nblocks, BDIM, 0, stream>>>(D1, D2, D3, cg, partials, batch);
    cg_reduce_kernel<<<1, BDIM, 0, stream>>>(partials, out, nblocks, inv);
}